// Round 4
// baseline (53.060 us; speedup 1.0000x reference)
//
#include <hip/hip_runtime.h>
#include <hip/hip_bf16.h>
#include <stdint.h>

typedef short short8 __attribute__((ext_vector_type(8)));
typedef float f32x4 __attribute__((ext_vector_type(4)));
typedef unsigned short ushort4_t __attribute__((ext_vector_type(4)));
typedef unsigned short ushort8_t __attribute__((ext_vector_type(8)));

#define S_LEN 2048
#define NQKV 1536
#define DMODEL 512

__device__ inline unsigned short f2bf(float f) {
  unsigned int u = __float_as_uint(f);
  unsigned int r = (u + 0x7FFFu + ((u >> 16) & 1u)) >> 16;
  return (unsigned short)r;
}

// async global->LDS, 16B per lane. LDS dest must be linear in lane order.
__device__ __forceinline__ void gll16(const unsigned short* g, unsigned short* l) {
  __builtin_amdgcn_global_load_lds(
      (const __attribute__((address_space(1))) unsigned int*)g,
      (__attribute__((address_space(3))) unsigned int*)l, 16, 0, 0);
}

// ---------------- fused prep: x->bf16, both weight transposes ----------------
__global__ __launch_bounds__(256) void k_prep(const float* __restrict__ x,
                                              unsigned short* __restrict__ xb,
                                              const float* __restrict__ w1,
                                              unsigned short* __restrict__ o1,
                                              const float* __restrict__ w2,
                                              unsigned short* __restrict__ o2) {
  __shared__ float T[32][33];
  int bid = blockIdx.x;
  int t = threadIdx.x;
  if (bid < 1024) {
    int i = (bid * 256 + t) * 8;
    float4 a = *(const float4*)(x + i);
    float4 b = *(const float4*)(x + i + 4);
    ushort8_t o;
    o[0] = f2bf(a.x); o[1] = f2bf(a.y); o[2] = f2bf(a.z); o[3] = f2bf(a.w);
    o[4] = f2bf(b.x); o[5] = f2bf(b.y); o[6] = f2bf(b.z); o[7] = f2bf(b.w);
    *(ushort8_t*)(xb + i) = o;
    return;
  }
  bid -= 1024;
  int bx = bid & 63, byy = bid >> 6;
  const float* w; unsigned short* o; int cols;
  if (bx < 48) { w = w1; o = o1; cols = 1536; }
  else         { w = w2; o = o2; cols = 512; bx -= 48; }
  int r0 = byy * 32, c0 = bx * 32;
  int tr = t / 32, tc = t % 32;
#pragma unroll
  for (int i = 0; i < 4; i++) {
    int r = tr + i * 8;
    T[r][tc] = w[(size_t)(r0 + r) * cols + c0 + tc];
  }
  __syncthreads();
#pragma unroll
  for (int i = 0; i < 4; i++) {
    int rr = tr + i * 8;
    o[(size_t)(c0 + rr) * 512 + r0 + tc] = f2bf(T[tc][rr]);
  }
}

// ---------------- GEMM: C[M][N] = A[M][K](bf16) * Bt[N][K](bf16)^T ----------------
// BMx128 tile, BK=32, 4 waves. Deep prefetch: 4 LDS buffers, 3 tiles in flight,
// counted vmcnt (never 0 in steady state), raw s_barrier (one per iter).
// MODE 0: f32 out + bias.  MODE 1: bf16 qkv out, with V-third scattered to vT.
template <int BM, int MODE>
__global__ __launch_bounds__(256) void k_gemm(const unsigned short* __restrict__ A,
                                              const unsigned short* __restrict__ Bt,
                                              void* __restrict__ Cout,
                                              const float* __restrict__ bias,
                                              unsigned short* __restrict__ vt,
                                              int M, int N, int K) {
  constexpr int MR = BM / 32;
  constexpr int CA = BM / 64;
  constexpr int LPT = CA + 2;  // gll16 insts per thread per tile
  __shared__ __align__(16) unsigned short As[4][BM * 32];
  __shared__ __align__(16) unsigned short Bs[4][128 * 32];
  const int t = threadIdx.x, lane = t & 63, wid = t >> 6;
  const int m0 = blockIdx.y * BM, n0 = blockIdx.x * 128;
  const int wm = (wid >> 1) * (BM / 2), wn = (wid & 1) * 64;
  const int lr = lane & 15, kr = (lane >> 4) * 8, lg = lane >> 4;
  const unsigned short* Ab = A + (size_t)m0 * K;
  const unsigned short* Bb = Bt + (size_t)n0 * K;
  f32x4 acc[MR][4] = {};

  const int NT = K / 32;  // = 16
  auto stage = [&](int buf, int it) {
    int kt = it * 32;
#pragma unroll
    for (int c = 0; c < CA; c++) {
      int f = t + 256 * c;
      gll16(Ab + (size_t)(f >> 2) * K + kt + (f & 3) * 8, &As[buf][f * 8]);
    }
#pragma unroll
    for (int c = 0; c < 2; c++) {
      int f = t + 256 * c;
      gll16(Bb + (size_t)(f >> 2) * K + kt + (f & 3) * 8, &Bs[buf][f * 8]);
    }
  };

  stage(0, 0); stage(1, 1); stage(2, 2);

  for (int it = 0; it < NT; ++it) {
    // Wait until tile `it` has landed: leave (tiles_in_flight-1)*LPT outstanding.
    if (it <= NT - 3) {
      if constexpr (LPT == 4) asm volatile("s_waitcnt vmcnt(8)" ::: "memory");
      else                    asm volatile("s_waitcnt vmcnt(6)" ::: "memory");
    } else if (it == NT - 2) {
      if constexpr (LPT == 4) asm volatile("s_waitcnt vmcnt(4)" ::: "memory");
      else                    asm volatile("s_waitcnt vmcnt(3)" ::: "memory");
    } else {
      asm volatile("s_waitcnt vmcnt(0)" ::: "memory");
    }
    __builtin_amdgcn_sched_barrier(0);
    __builtin_amdgcn_s_barrier();   // all waves' tile-it data visible; prev reads done
    __builtin_amdgcn_sched_barrier(0);
    if (it + 3 < NT) stage((it + 3) & 3, it + 3);

    const unsigned short* Ap = As[it & 3];
    const unsigned short* Bp = Bs[it & 3];
    short8 af[MR], bfv[4];
#pragma unroll
    for (int i = 0; i < MR; i++)
      af[i] = *(const short8*)&Ap[(wm + i * 16 + lr) * 32 + kr];
#pragma unroll
    for (int i = 0; i < 4; i++)
      bfv[i] = *(const short8*)&Bp[(wn + i * 16 + lr) * 32 + kr];
#pragma unroll
    for (int mi = 0; mi < MR; mi++)
#pragma unroll
      for (int ni = 0; ni < 4; ni++)
        acc[mi][ni] = __builtin_amdgcn_mfma_f32_16x16x32_bf16(af[mi], bfv[ni], acc[mi][ni], 0, 0, 0);
  }

#pragma unroll
  for (int mi = 0; mi < MR; mi++) {
#pragma unroll
    for (int ni = 0; ni < 4; ni++) {
      int col = n0 + wn + ni * 16 + lr;
      if (MODE == 0) {
        float bv = bias[col];
#pragma unroll
        for (int j = 0; j < 4; j++) {
          int row = m0 + wm + mi * 16 + lg * 4 + j;
          ((float*)Cout)[(size_t)row * N + col] = acc[mi][ni][j] + bv;
        }
      } else {
        int hh = col / 192, rr = col % 192;
#pragma unroll
        for (int j = 0; j < 4; j++) {
          int row = m0 + wm + mi * 16 + lg * 4 + j;
          unsigned short bv = f2bf(acc[mi][ni][j]);
          if (rr < 128) {
            ((unsigned short*)Cout)[(size_t)row * N + col] = bv;
          } else {
            int bb = row >> 11, pos = row & 2047;
            vt[((size_t)((bb * 8 + hh) * 64 + (rr - 128))) * 2048 + pos] = bv;
          }
        }
      }
    }
  }
}

// ---------------- windowed attention (no LDS, no barriers) ----------------
__global__ __launch_bounds__(256) void k_attn(const unsigned short* __restrict__ qkv,
                                              const unsigned short* __restrict__ vT,
                                              unsigned short* __restrict__ attn) {
  const int t = threadIdx.x, lane = t & 63, w = t >> 6;
  const int blk = blockIdx.x;
  const int sbi = blk & 31, h = (blk >> 5) & 7, b = blk >> 8;
  const int sb = sbi * 64;
  const unsigned short* base = qkv + (size_t)b * S_LEN * NQKV;
  const int lr = lane & 15, lg = lane >> 4;
  const int s0 = sb + w * 16;

  short8 qb[2];
#pragma unroll
  for (int ks = 0; ks < 2; ks++)
    qb[ks] = *(const short8*)(base + (size_t)(s0 + lr) * NQKV + h * 192 + ks * 32 + lg * 8);

  f32x4 sc[5] = {};
#pragma unroll
  for (int ct = 0; ct < 5; ct++) {
    int p = s0 - 32 + ct * 16 + lr;
    bool inb = (p >= 0 && p < S_LEN);
#pragma unroll
    for (int ks = 0; ks < 2; ks++) {
      short8 ka = {};
      if (inb)
        ka = *(const short8*)(base + (size_t)p * NQKV + h * 192 + 64 + ks * 32 + lg * 8);
      sc[ct] = __builtin_amdgcn_mfma_f32_16x16x32_bf16(ka, qb[ks], sc[ct], 0, 0, 0);
    }
  }

  float mx = -1e30f;
#pragma unroll
  for (int ct = 0; ct < 5; ct++)
#pragma unroll
    for (int j = 0; j < 4; j++) {
      int c2 = ct * 16 + lg * 4 + j;
      sc[ct][j] = (c2 >= lr && c2 <= lr + 64) ? sc[ct][j] * 0.125f : -1e30f;
      mx = fmaxf(mx, sc[ct][j]);
    }
  mx = fmaxf(mx, __shfl_xor(mx, 16, 64));
  mx = fmaxf(mx, __shfl_xor(mx, 32, 64));

  float pn[5][4];
  float sum = 0.0f;
#pragma unroll
  for (int ct = 0; ct < 5; ct++)
#pragma unroll
    for (int j = 0; j < 4; j++) {
      pn[ct][j] = __expf(sc[ct][j] - mx);
      sum += pn[ct][j];
    }
  sum += __shfl_xor(sum, 16, 64);
  sum += __shfl_xor(sum, 32, 64);
  float inv = 1.0f / sum;

  unsigned int w01[5], w23[5];
#pragma unroll
  for (int ct = 0; ct < 5; ct++) {
    float v[4];
#pragma unroll
    for (int j = 0; j < 4; j++) {
      int p = s0 - 32 + ct * 16 + lg * 4 + j;
      float xv = pn[ct][j] * inv;
      v[j] = (p >= 0 && p < S_LEN) ? xv : 0.0f;
    }
    w01[ct] = (unsigned int)f2bf(v[0]) | ((unsigned int)f2bf(v[1]) << 16);
    w23[ct] = (unsigned int)f2bf(v[2]) | ((unsigned int)f2bf(v[3]) << 16);
  }

  const unsigned short* vbase = vT + (size_t)((b * 8 + h) * 64) * 2048;
  f32x4 oa[4] = {};
  const int h2 = lg & 1, tl = lg >> 1;
  const int sA = 32 * h2 + lr, sB = sA + 16;
#pragma unroll
  for (int ks = 0; ks < 3; ks++) {
    const int T0 = 2 * ks;
    const int T1 = (2 * ks + 1 < 5) ? (2 * ks + 1) : 4;
    unsigned int a0 = __shfl((int)w01[T0], sA, 64), a1 = __shfl((int)w23[T0], sA, 64);
    unsigned int a2 = __shfl((int)w01[T0], sB, 64), a3 = __shfl((int)w23[T0], sB, 64);
    unsigned int b0 = __shfl((int)w01[T1], sA, 64), b1 = __shfl((int)w23[T1], sA, 64);
    unsigned int b2 = __shfl((int)w01[T1], sB, 64), b3 = __shfl((int)w23[T1], sB, 64);
    union { unsigned int u[4]; short8 v; } pb;
    pb.u[0] = tl ? b0 : a0;
    pb.u[1] = tl ? b1 : a1;
    pb.u[2] = tl ? b2 : a2;
    pb.u[3] = tl ? b3 : a3;
    if (ks == 2 && tl) { pb.u[0] = 0; pb.u[1] = 0; pb.u[2] = 0; pb.u[3] = 0; }
    int poff = s0 - 32 + ks * 32 + lg * 8;
#pragma unroll
    for (int nt = 0; nt < 4; nt++) {
      short8 va = *(const short8*)(vbase + (size_t)(nt * 16 + lr) * 2048 + poff);
      oa[nt] = __builtin_amdgcn_mfma_f32_16x16x32_bf16(va, pb.v, oa[nt], 0, 0, 0);
    }
  }

#pragma unroll
  for (int nt = 0; nt < 4; nt++) {
    ushort4_t o;
#pragma unroll
    for (int j = 0; j < 4; j++) o[j] = f2bf(oa[nt][j]);
    *(ushort4_t*)(attn + ((size_t)b * S_LEN + s0 + lr) * DMODEL + h * 64 + nt * 16 + lg * 4) = o;
  }
}

// ---------------- launch ----------------
extern "C" void kernel_launch(void* const* d_in, const int* in_sizes, int n_in,
                              void* d_out, int out_size, void* d_ws, size_t ws_size,
                              hipStream_t stream) {
  const float* x    = (const float*)d_in[0];
  const float* Wqkv = (const float*)d_in[1];
  const float* Wout = (const float*)d_in[2];
  const float* bout = (const float*)d_in[3];
  char* ws = (char*)d_ws;
  unsigned short* xb    = (unsigned short*)(ws + 0);         // 4096x512 bf16   (4 MB)
  unsigned short* wqkvt = (unsigned short*)(ws + 4194304);   // 1536x512 bf16   (1.5 MB)
  unsigned short* woutt = (unsigned short*)(ws + 5767168);   // 512x512 bf16    (0.5 MB)
  unsigned short* qkv   = (unsigned short*)(ws + 6291456);   // 4096x1536 bf16  (12 MB)
  unsigned short* attn  = (unsigned short*)(ws + 18874368);  // 4096x512 bf16   (4 MB)
  unsigned short* vT    = (unsigned short*)(ws + 23068672);  // [2][8][64][2048] (4 MB)

  hipLaunchKernelGGL(k_prep, dim3(2048), dim3(256), 0, stream,
                     x, xb, Wqkv, wqkvt, Wout, woutt);
  hipLaunchKernelGGL((k_gemm<128, 1>), dim3(12, 32), dim3(256), 0, stream,
                     xb, wqkvt, (void*)qkv, (const float*)nullptr, vT, 4096, 1536, 512);
  hipLaunchKernelGGL(k_attn, dim3(512), dim3(256), 0, stream, qkv, vT, attn);
  hipLaunchKernelGGL((k_gemm<64, 0>), dim3(4, 64), dim3(256), 0, stream,
                     attn, woutt, d_out, bout, (unsigned short*)nullptr, 4096, 512, 512);
}

// Round 6
// 44.309 us; speedup vs baseline: 1.1975x; 1.1975x over previous
//
#include <hip/hip_runtime.h>
#include <hip/hip_bf16.h>
#include <stdint.h>

typedef short short8 __attribute__((ext_vector_type(8)));
typedef float f32x4 __attribute__((ext_vector_type(4)));
typedef unsigned short ushort4_t __attribute__((ext_vector_type(4)));
typedef unsigned short ushort8_t __attribute__((ext_vector_type(8)));

#define S_LEN 2048
#define NQKV 1536
#define DMODEL 512

__device__ inline unsigned short f2bf(float f) {
  unsigned int u = __float_as_uint(f);
  unsigned int r = (u + 0x7FFFu + ((u >> 16) & 1u)) >> 16;
  return (unsigned short)r;
}

// async global->LDS, 16B per lane. LDS dest must be linear in lane order.
__device__ __forceinline__ void gll16(const unsigned short* g, unsigned short* l) {
  __builtin_amdgcn_global_load_lds(
      (const __attribute__((address_space(1))) unsigned int*)g,
      (__attribute__((address_space(3))) unsigned int*)l, 16, 0, 0);
}

// ---------------- fused prep: x->bf16, both weight transposes ----------------
__global__ __launch_bounds__(256) void k_prep(const float* __restrict__ x,
                                              unsigned short* __restrict__ xb,
                                              const float* __restrict__ w1,
                                              unsigned short* __restrict__ o1,
                                              const float* __restrict__ w2,
                                              unsigned short* __restrict__ o2) {
  __shared__ float T[32][33];
  int bid = blockIdx.x;
  int t = threadIdx.x;
  if (bid < 1024) {
    int i = (bid * 256 + t) * 8;
    float4 a = *(const float4*)(x + i);
    float4 b = *(const float4*)(x + i + 4);
    ushort8_t o;
    o[0] = f2bf(a.x); o[1] = f2bf(a.y); o[2] = f2bf(a.z); o[3] = f2bf(a.w);
    o[4] = f2bf(b.x); o[5] = f2bf(b.y); o[6] = f2bf(b.z); o[7] = f2bf(b.w);
    *(ushort8_t*)(xb + i) = o;
    return;
  }
  bid -= 1024;
  int bx = bid & 63, byy = bid >> 6;
  const float* w; unsigned short* o; int cols;
  if (bx < 48) { w = w1; o = o1; cols = 1536; }
  else         { w = w2; o = o2; cols = 512; bx -= 48; }
  int r0 = byy * 32, c0 = bx * 32;
  int tr = t / 32, tc = t % 32;
#pragma unroll
  for (int i = 0; i < 4; i++) {
    int r = tr + i * 8;
    T[r][tc] = w[(size_t)(r0 + r) * cols + c0 + tc];
  }
  __syncthreads();
#pragma unroll
  for (int i = 0; i < 4; i++) {
    int rr = tr + i * 8;
    o[(size_t)(c0 + rr) * 512 + r0 + tc] = f2bf(T[tc][rr]);
  }
}

// ---------------- GEMM: C[M][N] = A[M][K](bf16) * Bt[N][K](bf16)^T ----------------
// BMx128 tile, BK=32, 4 waves, global_load_lds staging, 2-phase double buffer.
// MODE 0: f32 out + bias, direct stores.
// MODE 1: bf16 qkv out via swizzled-LDS bounce; V-third transposed to vT with
//         coalesced 16B stores (replaces 64-segment scalar u16 scatters).
template <int BM, int MODE>
__global__ __launch_bounds__(256) void k_gemm(const unsigned short* __restrict__ A,
                                              const unsigned short* __restrict__ Bt,
                                              void* __restrict__ Cout,
                                              const float* __restrict__ bias,
                                              unsigned short* __restrict__ vt,
                                              int M, int N, int K) {
  constexpr int MR = BM / 32;
  constexpr int CA = BM / 64;
  constexpr int STAGE_SH = 2 * BM * 32 + 2 * 128 * 32;      // shorts
  constexpr int SMEM_SH = (MODE == 1 && 128 * 128 > STAGE_SH) ? 128 * 128 : STAGE_SH;
  __shared__ __align__(16) unsigned short smem[SMEM_SH];
  // buffer offsets (avoid LDS pointer arrays -> addrspacecast static-init error)
  const int ASZ = BM * 32, BOFF = 2 * BM * 32, BSZ = 128 * 32;

  const int t = threadIdx.x, lane = t & 63, wid = t >> 6;
  const int m0 = blockIdx.y * BM, n0 = blockIdx.x * 128;
  const int wm = (wid >> 1) * (BM / 2), wn = (wid & 1) * 64;
  const int lr = lane & 15, kr = (lane >> 4) * 8, lg = lane >> 4;
  const unsigned short* Ab = A + (size_t)m0 * K;
  const unsigned short* Bb = Bt + (size_t)n0 * K;
  f32x4 acc[MR][4] = {};

  const int NT = K / 32;
  auto stage = [&](int buf, int kt) {
#pragma unroll
    for (int c = 0; c < CA; c++) {
      int f = t + 256 * c;
      gll16(Ab + (size_t)(f >> 2) * K + kt + (f & 3) * 8, &smem[buf * ASZ + f * 8]);
    }
#pragma unroll
    for (int c = 0; c < 2; c++) {
      int f = t + 256 * c;
      gll16(Bb + (size_t)(f >> 2) * K + kt + (f & 3) * 8, &smem[BOFF + buf * BSZ + f * 8]);
    }
  };

  stage(0, 0);
  int buf = 0;
  for (int it = 0; it < NT; ++it) {
    __syncthreads();
    if (it + 1 < NT) stage(buf ^ 1, (it + 1) * 32);
    const unsigned short* Ap = &smem[buf * ASZ];
    const unsigned short* Bp = &smem[BOFF + buf * BSZ];
    short8 af[MR], bfv[4];
#pragma unroll
    for (int i = 0; i < MR; i++)
      af[i] = *(const short8*)&Ap[(wm + i * 16 + lr) * 32 + kr];
#pragma unroll
    for (int i = 0; i < 4; i++)
      bfv[i] = *(const short8*)&Bp[(wn + i * 16 + lr) * 32 + kr];
#pragma unroll
    for (int mi = 0; mi < MR; mi++)
#pragma unroll
      for (int ni = 0; ni < 4; ni++)
        acc[mi][ni] = __builtin_amdgcn_mfma_f32_16x16x32_bf16(af[mi], bfv[ni], acc[mi][ni], 0, 0, 0);
    buf ^= 1;
  }

  if (MODE == 0) {
#pragma unroll
    for (int mi = 0; mi < MR; mi++) {
#pragma unroll
      for (int ni = 0; ni < 4; ni++) {
        int col = n0 + wn + ni * 16 + lr;
        float bv = bias[col];
#pragma unroll
        for (int j = 0; j < 4; j++) {
          int row = m0 + wm + mi * 16 + lg * 4 + j;
          ((float*)Cout)[(size_t)row * N + col] = acc[mi][ni][j] + bv;
        }
      }
    }
  } else {
    // ---- swizzled LDS bounce: smem as C-tile [128 rows][128 cols] bf16 ----
    // u16 index = row*128 + (col ^ (((row>>3)&7)<<3))   (16B-chunk XOR swizzle)
    __syncthreads();  // all waves done reading stage buffers
#pragma unroll
    for (int mi = 0; mi < MR; mi++)
#pragma unroll
      for (int ni = 0; ni < 4; ni++)
#pragma unroll
        for (int j = 0; j < 4; j++) {
          int row = wm + mi * 16 + lg * 4 + j;
          int col = wn + ni * 16 + lr;
          smem[row * 128 + (col ^ (((row >> 3) & 7) << 3))] = f2bf(acc[mi][ni][j]);
        }
    __syncthreads();

    unsigned short* qkvout = (unsigned short*)Cout;
    const int b_ = m0 >> 11;
    const int posb = m0 & 2047;
#pragma unroll
    for (int hf = 0; hf < 2; hf++) {
      int c_abs = n0 + hf * 64;
      int g = c_abs % 192;
      if (g < 128) {
        // Q/K half: 128 rows x 64 cols -> 16B coalesced stores
#pragma unroll
        for (int i = 0; i < 4; i++) {
          int s = t + 256 * i;            // 1024 chunks of 8 u16
          int row = s >> 3, ch = s & 7;
          int src = row * 128 + ((hf * 64 + ch * 8) ^ (((row >> 3) & 7) << 3));
          ushort8_t v = *(const ushort8_t*)&smem[src];
          *(ushort8_t*)&qkvout[(size_t)(m0 + row) * NQKV + c_abs + ch * 8] = v;
        }
      } else {
        // V half: transpose to vT[d][pos]; 16 lanes cover 256B contiguous pos
        int h = c_abs / 192, d0 = g - 128;
#pragma unroll
        for (int i = 0; i < 4; i++) {
          int s = t + 256 * i;            // dl = s>>4 (0..63), pc = s&15
          int dl = s >> 4, pc = s & 15;
          ushort8_t v;
#pragma unroll
          for (int j = 0; j < 8; j++) {
            int row = pc * 8 + j;
            v[j] = smem[row * 128 + ((hf * 64 + dl) ^ (((row >> 3) & 7) << 3))];
          }
          *(ushort8_t*)&vt[((size_t)((b_ * 8 + h) * 64 + d0 + dl)) * 2048 + posb + pc * 8] = v;
        }
      }
    }
  }
}

// ---------------- windowed attention (no LDS, no barriers) ----------------
__global__ __launch_bounds__(256) void k_attn(const unsigned short* __restrict__ qkv,
                                              const unsigned short* __restrict__ vT,
                                              unsigned short* __restrict__ attn) {
  const int t = threadIdx.x, lane = t & 63, w = t >> 6;
  const int blk = blockIdx.x;
  const int sbi = blk & 31, h = (blk >> 5) & 7, b = blk >> 8;
  const int sb = sbi * 64;
  const unsigned short* base = qkv + (size_t)b * S_LEN * NQKV;
  const int lr = lane & 15, lg = lane >> 4;
  const int s0 = sb + w * 16;

  short8 qb[2];
#pragma unroll
  for (int ks = 0; ks < 2; ks++)
    qb[ks] = *(const short8*)(base + (size_t)(s0 + lr) * NQKV + h * 192 + ks * 32 + lg * 8);

  f32x4 sc[5] = {};
#pragma unroll
  for (int ct = 0; ct < 5; ct++) {
    int p = s0 - 32 + ct * 16 + lr;
    bool inb = (p >= 0 && p < S_LEN);
#pragma unroll
    for (int ks = 0; ks < 2; ks++) {
      short8 ka = {};
      if (inb)
        ka = *(const short8*)(base + (size_t)p * NQKV + h * 192 + 64 + ks * 32 + lg * 8);
      sc[ct] = __builtin_amdgcn_mfma_f32_16x16x32_bf16(ka, qb[ks], sc[ct], 0, 0, 0);
    }
  }

  float mx = -1e30f;
#pragma unroll
  for (int ct = 0; ct < 5; ct++)
#pragma unroll
    for (int j = 0; j < 4; j++) {
      int c2 = ct * 16 + lg * 4 + j;
      sc[ct][j] = (c2 >= lr && c2 <= lr + 64) ? sc[ct][j] * 0.125f : -1e30f;
      mx = fmaxf(mx, sc[ct][j]);
    }
  mx = fmaxf(mx, __shfl_xor(mx, 16, 64));
  mx = fmaxf(mx, __shfl_xor(mx, 32, 64));

  float pn[5][4];
  float sum = 0.0f;
#pragma unroll
  for (int ct = 0; ct < 5; ct++)
#pragma unroll
    for (int j = 0; j < 4; j++) {
      pn[ct][j] = __expf(sc[ct][j] - mx);
      sum += pn[ct][j];
    }
  sum += __shfl_xor(sum, 16, 64);
  sum += __shfl_xor(sum, 32, 64);
  float inv = 1.0f / sum;

  unsigned int w01[5], w23[5];
#pragma unroll
  for (int ct = 0; ct < 5; ct++) {
    float v[4];
#pragma unroll
    for (int j = 0; j < 4; j++) {
      int p = s0 - 32 + ct * 16 + lg * 4 + j;
      float xv = pn[ct][j] * inv;
      v[j] = (p >= 0 && p < S_LEN) ? xv : 0.0f;
    }
    w01[ct] = (unsigned int)f2bf(v[0]) | ((unsigned int)f2bf(v[1]) << 16);
    w23[ct] = (unsigned int)f2bf(v[2]) | ((unsigned int)f2bf(v[3]) << 16);
  }

  const unsigned short* vbase = vT + (size_t)((b * 8 + h) * 64) * 2048;
  f32x4 oa[4] = {};
  const int h2 = lg & 1, tl = lg >> 1;
  const int sA = 32 * h2 + lr, sB = sA + 16;
#pragma unroll
  for (int ks = 0; ks < 3; ks++) {
    const int T0 = 2 * ks;
    const int T1 = (2 * ks + 1 < 5) ? (2 * ks + 1) : 4;
    unsigned int a0 = __shfl((int)w01[T0], sA, 64), a1 = __shfl((int)w23[T0], sA, 64);
    unsigned int a2 = __shfl((int)w01[T0], sB, 64), a3 = __shfl((int)w23[T0], sB, 64);
    unsigned int b0 = __shfl((int)w01[T1], sA, 64), b1 = __shfl((int)w23[T1], sA, 64);
    unsigned int b2 = __shfl((int)w01[T1], sB, 64), b3 = __shfl((int)w23[T1], sB, 64);
    union { unsigned int u[4]; short8 v; } pb;
    pb.u[0] = tl ? b0 : a0;
    pb.u[1] = tl ? b1 : a1;
    pb.u[2] = tl ? b2 : a2;
    pb.u[3] = tl ? b3 : a3;
    if (ks == 2 && tl) { pb.u[0] = 0; pb.u[1] = 0; pb.u[2] = 0; pb.u[3] = 0; }
    int poff = s0 - 32 + ks * 32 + lg * 8;
#pragma unroll
    for (int nt = 0; nt < 4; nt++) {
      short8 va = *(const short8*)(vbase + (size_t)(nt * 16 + lr) * 2048 + poff);
      oa[nt] = __builtin_amdgcn_mfma_f32_16x16x32_bf16(va, pb.v, oa[nt], 0, 0, 0);
    }
  }

#pragma unroll
  for (int nt = 0; nt < 4; nt++) {
    ushort4_t o;
#pragma unroll
    for (int j = 0; j < 4; j++) o[j] = f2bf(oa[nt][j]);
    *(ushort4_t*)(attn + ((size_t)b * S_LEN + s0 + lr) * DMODEL + h * 64 + nt * 16 + lg * 4) = o;
  }
}

// ---------------- launch ----------------
extern "C" void kernel_launch(void* const* d_in, const int* in_sizes, int n_in,
                              void* d_out, int out_size, void* d_ws, size_t ws_size,
                              hipStream_t stream) {
  const float* x    = (const float*)d_in[0];
  const float* Wqkv = (const float*)d_in[1];
  const float* Wout = (const float*)d_in[2];
  const float* bout = (const float*)d_in[3];
  char* ws = (char*)d_ws;
  unsigned short* xb    = (unsigned short*)(ws + 0);         // 4096x512 bf16   (4 MB)
  unsigned short* wqkvt = (unsigned short*)(ws + 4194304);   // 1536x512 bf16   (1.5 MB)
  unsigned short* woutt = (unsigned short*)(ws + 5767168);   // 512x512 bf16    (0.5 MB)
  unsigned short* qkv   = (unsigned short*)(ws + 6291456);   // 4096x1536 bf16  (12 MB)
  unsigned short* attn  = (unsigned short*)(ws + 18874368);  // 4096x512 bf16   (4 MB)
  unsigned short* vT    = (unsigned short*)(ws + 23068672);  // [2][8][64][2048] (4 MB)

  hipLaunchKernelGGL(k_prep, dim3(2048), dim3(256), 0, stream,
                     x, xb, Wqkv, wqkvt, Wout, woutt);
  hipLaunchKernelGGL((k_gemm<128, 1>), dim3(12, 32), dim3(256), 0, stream,
                     xb, wqkvt, (void*)qkv, (const float*)nullptr, vT, 4096, 1536, 512);
  hipLaunchKernelGGL(k_attn, dim3(512), dim3(256), 0, stream, qkv, vT, attn);
  hipLaunchKernelGGL((k_gemm<64, 0>), dim3(4, 64), dim3(256), 0, stream,
                     attn, woutt, d_out, bout, (unsigned short*)nullptr, 4096, 512, 512);
}

// Round 7
// 42.337 us; speedup vs baseline: 1.2533x; 1.0466x over previous
//
#include <hip/hip_runtime.h>
#include <hip/hip_bf16.h>
#include <stdint.h>

typedef short short8 __attribute__((ext_vector_type(8)));
typedef float f32x4 __attribute__((ext_vector_type(4)));
typedef unsigned short ushort4_t __attribute__((ext_vector_type(4)));
typedef unsigned short ushort8_t __attribute__((ext_vector_type(8)));

#define S_LEN 2048
#define NQKV 1536
#define DMODEL 512

__device__ inline unsigned short f2bf(float f) {
  unsigned int u = __float_as_uint(f);
  unsigned int r = (u + 0x7FFFu + ((u >> 16) & 1u)) >> 16;
  return (unsigned short)r;
}

// async global->LDS, 16B per lane. LDS dest must be linear in lane order.
__device__ __forceinline__ void gll16(const unsigned short* g, unsigned short* l) {
  __builtin_amdgcn_global_load_lds(
      (const __attribute__((address_space(1))) unsigned int*)g,
      (__attribute__((address_space(3))) unsigned int*)l, 16, 0, 0);
}

// ---------------- fused prep: x->bf16, weight transposes, pad zeroing --------
__global__ __launch_bounds__(256) void k_prep(const float* __restrict__ x,
                                              unsigned short* __restrict__ xb,
                                              const float* __restrict__ w1,
                                              unsigned short* __restrict__ o1,
                                              const float* __restrict__ w2,
                                              unsigned short* __restrict__ o2,
                                              unsigned short* __restrict__ Kp,
                                              unsigned short* __restrict__ Vp) {
  __shared__ float T[32][33];
  int bid = blockIdx.x;
  int t = threadIdx.x;
  if (bid < 1024) {
    int i = (bid * 256 + t) * 8;
    float4 a = *(const float4*)(x + i);
    float4 b = *(const float4*)(x + i + 4);
    ushort8_t o;
    o[0] = f2bf(a.x); o[1] = f2bf(a.y); o[2] = f2bf(a.z); o[3] = f2bf(a.w);
    o[4] = f2bf(b.x); o[5] = f2bf(b.y); o[6] = f2bf(b.z); o[7] = f2bf(b.w);
    *(ushort8_t*)(xb + i) = o;
    return;
  }
  if (bid >= 2048) {  // pad zeroing: Kp rows [0,32)+[2080,2112); Vp cols same
    int p = bid - 2048;
    ushort8_t z = {};
    if (p < 16) {
      unsigned short* dst = Kp + (size_t)p * 2112 * 64;
#pragma unroll
      for (int i = 0; i < 2; i++) {
        int s = t + 256 * i;              // 512 chunks: 64 rows x 8
        int row = s >> 3, c = s & 7;
        int r2 = row < 32 ? row : row - 32 + 2080;
        *(ushort8_t*)&dst[r2 * 64 + c * 8] = z;
      }
    } else {
      unsigned short* dst = Vp + (size_t)(p - 16) * 64 * 2112;
#pragma unroll
      for (int i = 0; i < 2; i++) {
        int s = t + 256 * i;              // 512 chunks: 64 d x 2 sides x 4
        int d = s >> 3, side = (s >> 2) & 1, c = s & 3;
        *(ushort8_t*)&dst[(size_t)d * 2112 + side * 2080 + c * 8] = z;
      }
    }
    return;
  }
  bid -= 1024;
  int bx = bid & 63, byy = bid >> 6;
  const float* w; unsigned short* o; int cols;
  if (bx < 48) { w = w1; o = o1; cols = 1536; }
  else         { w = w2; o = o2; cols = 512; bx -= 48; }
  int r0 = byy * 32, c0 = bx * 32;
  int tr = t / 32, tc = t % 32;
#pragma unroll
  for (int i = 0; i < 4; i++) {
    int r = tr + i * 8;
    T[r][tc] = w[(size_t)(r0 + r) * cols + c0 + tc];
  }
  __syncthreads();
#pragma unroll
  for (int i = 0; i < 4; i++) {
    int rr = tr + i * 8;
    o[(size_t)(c0 + rr) * 512 + r0 + tc] = f2bf(T[tc][rr]);
  }
}

// ---------------- GEMM: C[M][N] = A[M][K](bf16) * Bt[N][K](bf16)^T ----------------
// BMx128 tile, BK=32, 4 waves, global_load_lds staging, 2-phase double buffer.
// MODE 0: f32 out + bias via LDS bounce, coalesced float4 stores.
// MODE 1: outputs de-interleaved Qs / Kp(+32 pad offset) / Vp(transposed) via
//         swizzled-LDS bounce, all-contiguous 16B stores.
template <int BM, int MODE>
__global__ __launch_bounds__(256) void k_gemm(const unsigned short* __restrict__ A,
                                              const unsigned short* __restrict__ Bt,
                                              void* __restrict__ Cout,
                                              const float* __restrict__ bias,
                                              unsigned short* __restrict__ qs,
                                              unsigned short* __restrict__ kp,
                                              unsigned short* __restrict__ vp,
                                              int M, int N, int K) {
  constexpr int MR = BM / 32;
  constexpr int CA = BM / 64;
  constexpr int STAGE_SH = 2 * BM * 32 + 2 * 128 * 32;  // shorts
  constexpr int BOUNCE_SH = 16384;                       // 128x128 bf16 or 64x128 f32
  constexpr int SMEM_SH = STAGE_SH > BOUNCE_SH ? STAGE_SH : BOUNCE_SH;
  __shared__ __align__(16) unsigned short smem[SMEM_SH];
  const int ASZ = BM * 32, BOFF = 2 * BM * 32, BSZ = 128 * 32;

  const int t = threadIdx.x, lane = t & 63, wid = t >> 6;
  const int m0 = blockIdx.y * BM, n0 = blockIdx.x * 128;
  const int wm = (wid >> 1) * (BM / 2), wn = (wid & 1) * 64;
  const int lr = lane & 15, kr = (lane >> 4) * 8, lg = lane >> 4;
  const unsigned short* Ab = A + (size_t)m0 * K;
  const unsigned short* Bb = Bt + (size_t)n0 * K;
  f32x4 acc[MR][4] = {};

  const int NT = K / 32;
  auto stage = [&](int buf, int kt) {
#pragma unroll
    for (int c = 0; c < CA; c++) {
      int f = t + 256 * c;
      gll16(Ab + (size_t)(f >> 2) * K + kt + (f & 3) * 8, &smem[buf * ASZ + f * 8]);
    }
#pragma unroll
    for (int c = 0; c < 2; c++) {
      int f = t + 256 * c;
      gll16(Bb + (size_t)(f >> 2) * K + kt + (f & 3) * 8, &smem[BOFF + buf * BSZ + f * 8]);
    }
  };

  stage(0, 0);
  int buf = 0;
  for (int it = 0; it < NT; ++it) {
    __syncthreads();
    if (it + 1 < NT) stage(buf ^ 1, (it + 1) * 32);
    const unsigned short* Ap = &smem[buf * ASZ];
    const unsigned short* Bp = &smem[BOFF + buf * BSZ];
    short8 af[MR], bfv[4];
#pragma unroll
    for (int i = 0; i < MR; i++)
      af[i] = *(const short8*)&Ap[(wm + i * 16 + lr) * 32 + kr];
#pragma unroll
    for (int i = 0; i < 4; i++)
      bfv[i] = *(const short8*)&Bp[(wn + i * 16 + lr) * 32 + kr];
#pragma unroll
    for (int mi = 0; mi < MR; mi++)
#pragma unroll
      for (int ni = 0; ni < 4; ni++)
        acc[mi][ni] = __builtin_amdgcn_mfma_f32_16x16x32_bf16(af[mi], bfv[ni], acc[mi][ni], 0, 0, 0);
    buf ^= 1;
  }

  if (MODE == 0) {
    // ---- f32 bounce: [BM rows][128 cols] f32, coalesced float4 stores ----
    __syncthreads();
    float* ft = (float*)smem;
#pragma unroll
    for (int mi = 0; mi < MR; mi++)
#pragma unroll
      for (int ni = 0; ni < 4; ni++)
#pragma unroll
        for (int j = 0; j < 4; j++)
          ft[(wm + mi * 16 + lg * 4 + j) * 128 + wn + ni * 16 + lr] = acc[mi][ni][j];
    __syncthreads();
#pragma unroll
    for (int i = 0; i < BM / 8; i++) {
      int s = t + 256 * i;
      int row = s >> 5, ch = s & 31;
      float4 v = *(const float4*)&ft[row * 128 + ch * 4];
      float4 bv = *(const float4*)&bias[n0 + ch * 4];
      v.x += bv.x; v.y += bv.y; v.z += bv.z; v.w += bv.w;
      *(float4*)&((float*)Cout)[(size_t)(m0 + row) * N + n0 + ch * 4] = v;
    }
  } else {
    // ---- swizzled bf16 bounce [128][128]; u16 idx = row*128 + (col ^ (((row>>3)&7)<<3))
    __syncthreads();
#pragma unroll
    for (int mi = 0; mi < MR; mi++)
#pragma unroll
      for (int ni = 0; ni < 4; ni++)
#pragma unroll
        for (int j = 0; j < 4; j++) {
          int row = wm + mi * 16 + lg * 4 + j;
          int col = wn + ni * 16 + lr;
          smem[row * 128 + (col ^ (((row >> 3) & 7) << 3))] = f2bf(acc[mi][ni][j]);
        }
    __syncthreads();

    const int b_ = m0 >> 11;
    const int posb = m0 & 2047;
#pragma unroll
    for (int hf = 0; hf < 2; hf++) {
      int c_abs = n0 + hf * 64;
      int h = c_abs / 192, seg = (c_abs % 192) >> 6;  // 0=q, 1=k, 2=v (64-col pure)
      if (seg < 2) {
        unsigned short* dst = (seg == 0)
            ? qs + ((size_t)(b_ * 8 + h) * 2048 + posb) * 64
            : kp + ((size_t)(b_ * 8 + h) * 2112 + 32 + posb) * 64;
#pragma unroll
        for (int i = 0; i < 4; i++) {
          int s = t + 256 * i;            // 1024 chunks: 128 rows x 8
          int row = s >> 3, ch = s & 7;
          int src = row * 128 + ((hf * 64 + ch * 8) ^ (((row >> 3) & 7) << 3));
          *(ushort8_t*)&dst[s * 8] = *(const ushort8_t*)&smem[src];
        }
      } else {
        unsigned short* dst = vp + (size_t)(b_ * 8 + h) * 64 * 2112;
#pragma unroll
        for (int i = 0; i < 4; i++) {
          int s = t + 256 * i;            // dl 0..63, pc 0..15
          int dl = s >> 4, pc = s & 15;
          ushort8_t v;
#pragma unroll
          for (int j = 0; j < 8; j++) {
            int row = pc * 8 + j;
            v[j] = smem[row * 128 + ((hf * 64 + dl) ^ (((row >> 3) & 7) << 3))];
          }
          *(ushort8_t*)&dst[(size_t)dl * 2112 + 32 + posb + pc * 8] = v;
        }
      }
    }
  }
}

// ---------------- windowed attention: LDS-staged, swizzled, branch-free ------
// Block = (b, h, 64 q), 4 waves x 16 q. All tiles staged via gll16 with
// source-chunk XOR; ds_reads apply the same XOR (rule-21 both-sides swizzle).
__global__ __launch_bounds__(256) void k_attn(const unsigned short* __restrict__ Qs,
                                              const unsigned short* __restrict__ Kp,
                                              const unsigned short* __restrict__ Vp,
                                              unsigned short* __restrict__ attnb) {
  __shared__ __align__(16) unsigned short Kt[128 * 64];  // pos-local x d, swz
  __shared__ __align__(16) unsigned short Vt[64 * 192];  // d x pos-local, swz
  __shared__ __align__(16) unsigned short Qt[64 * 64];   // q-local x d, swz
  const int t = threadIdx.x, lane = t & 63, w = t >> 6;
  const int blk = blockIdx.x;
  const int sbi = blk & 31, h = (blk >> 5) & 7, b = blk >> 8;
  const int sb = sbi * 64;
  const int bh = b * 8 + h;
  const int lr = lane & 15, lg = lane >> 4;

  {  // stage K: Kp idx sb..sb+127 (= global pos sb-32..sb+95)
    const unsigned short* src = Kp + ((size_t)bh * 2112 + sb) * 64;
#pragma unroll
    for (int i = 0; i < 4; i++) {
      int s = t + 256 * i, row = s >> 3, c = s & 7;
      gll16(src + row * 64 + (c ^ (row & 7)) * 8, &Kt[s * 8]);
    }
  }
  {  // stage V: Vp cols sb..sb+191 (= global pos sb-32..sb+159)
    const unsigned short* src = Vp + (size_t)bh * 64 * 2112 + sb;
#pragma unroll
    for (int i = 0; i < 6; i++) {
      int s = t + 256 * i, d = s / 24, c = s - d * 24;
      gll16(src + (size_t)d * 2112 + (c ^ (d & 7)) * 8, &Vt[s * 8]);
    }
  }
  {  // stage Q: rows sb..sb+63
    const unsigned short* src = Qs + ((size_t)bh * 2048 + sb) * 64;
#pragma unroll
    for (int i = 0; i < 2; i++) {
      int s = t + 256 * i, row = s >> 3, c = s & 7;
      gll16(src + row * 64 + (c ^ (row & 7)) * 8, &Qt[s * 8]);
    }
  }
  __syncthreads();

  const int sw = (lr & 7) << 3;  // u16 read-XOR (16B chunks)

  short8 qb[2];
#pragma unroll
  for (int ks = 0; ks < 2; ks++)
    qb[ks] = *(const short8*)&Qt[(w * 16 + lr) * 64 + ((ks * 32 + lg * 8) ^ sw)];

  // S^T: col = q = lr, row = pos_local(rel s0-32) = ct*16 + lg*4 + j
  f32x4 sc[5] = {};
#pragma unroll
  for (int ct = 0; ct < 5; ct++) {
#pragma unroll
    for (int ks = 0; ks < 2; ks++) {
      short8 ka = *(const short8*)&Kt[(w * 16 + ct * 16 + lr) * 64 + ((ks * 32 + lg * 8) ^ sw)];
      sc[ct] = __builtin_amdgcn_mfma_f32_16x16x32_bf16(ka, qb[ks], sc[ct], 0, 0, 0);
    }
  }

  float mx = -1e30f;
#pragma unroll
  for (int ct = 0; ct < 5; ct++)
#pragma unroll
    for (int j = 0; j < 4; j++) {
      int c2 = ct * 16 + lg * 4 + j;
      sc[ct][j] = (c2 >= lr && c2 <= lr + 64) ? sc[ct][j] * 0.125f : -1e30f;
      mx = fmaxf(mx, sc[ct][j]);
    }
  mx = fmaxf(mx, __shfl_xor(mx, 16, 64));
  mx = fmaxf(mx, __shfl_xor(mx, 32, 64));

  float pn[5][4];
  float sum = 0.0f;
#pragma unroll
  for (int ct = 0; ct < 5; ct++)
#pragma unroll
    for (int j = 0; j < 4; j++) {
      pn[ct][j] = __expf(sc[ct][j] - mx);
      sum += pn[ct][j];
    }
  sum += __shfl_xor(sum, 16, 64);
  sum += __shfl_xor(sum, 32, 64);
  float inv = 1.0f / sum;

  // Pack P^T (pad positions multiply zero-padded V -> no bounds logic needed)
  unsigned int w01[5], w23[5];
#pragma unroll
  for (int ct = 0; ct < 5; ct++) {
    w01[ct] = (unsigned int)f2bf(pn[ct][0] * inv) | ((unsigned int)f2bf(pn[ct][1] * inv) << 16);
    w23[ct] = (unsigned int)f2bf(pn[ct][2] * inv) | ((unsigned int)f2bf(pn[ct][3] * inv) << 16);
  }

  // PV: O^T[d][q], contraction over 96 local pos (3 k-slices of 32)
  f32x4 oa[4] = {};
  const int h2 = lg & 1, tl = lg >> 1;
  const int sA = 32 * h2 + lr, sB = sA + 16;
#pragma unroll
  for (int ks = 0; ks < 3; ks++) {
    const int T0 = 2 * ks;
    const int T1 = (2 * ks + 1 < 5) ? (2 * ks + 1) : 4;
    unsigned int a0 = __shfl((int)w01[T0], sA, 64), a1 = __shfl((int)w23[T0], sA, 64);
    unsigned int a2 = __shfl((int)w01[T0], sB, 64), a3 = __shfl((int)w23[T0], sB, 64);
    unsigned int b0 = __shfl((int)w01[T1], sA, 64), b1 = __shfl((int)w23[T1], sA, 64);
    unsigned int b2 = __shfl((int)w01[T1], sB, 64), b3 = __shfl((int)w23[T1], sB, 64);
    union { unsigned int u[4]; short8 v; } pb;
    pb.u[0] = tl ? b0 : a0;
    pb.u[1] = tl ? b1 : a1;
    pb.u[2] = tl ? b2 : a2;
    pb.u[3] = tl ? b3 : a3;
    if (ks == 2 && tl) { pb.u[0] = 0; pb.u[1] = 0; pb.u[2] = 0; pb.u[3] = 0; }
    int pofl = w * 16 + ks * 32 + lg * 8;  // local pos (rel sb-32)
#pragma unroll
    for (int nt = 0; nt < 4; nt++) {
      short8 va = *(const short8*)&Vt[(nt * 16 + lr) * 192 + (pofl ^ sw)];
      oa[nt] = __builtin_amdgcn_mfma_f32_16x16x32_bf16(va, pb.v, oa[nt], 0, 0, 0);
    }
  }

  const int s0 = sb + w * 16;
#pragma unroll
  for (int nt = 0; nt < 4; nt++) {
    ushort4_t o;
#pragma unroll
    for (int j = 0; j < 4; j++) o[j] = f2bf(oa[nt][j]);
    *(ushort4_t*)&attnb[((size_t)b * S_LEN + s0 + lr) * DMODEL + h * 64 + nt * 16 + lg * 4] = o;
  }
}

// ---------------- launch ----------------
extern "C" void kernel_launch(void* const* d_in, const int* in_sizes, int n_in,
                              void* d_out, int out_size, void* d_ws, size_t ws_size,
                              hipStream_t stream) {
  const float* x    = (const float*)d_in[0];
  const float* Wqkv = (const float*)d_in[1];
  const float* Wout = (const float*)d_in[2];
  const float* bout = (const float*)d_in[3];
  char* ws = (char*)d_ws;
  unsigned short* xb    = (unsigned short*)(ws + 0);         // 4096x512 bf16 (4 MB)
  unsigned short* wqkvt = (unsigned short*)(ws + 4194304);   // 1536x512 bf16 (1.5 MB)
  unsigned short* woutt = (unsigned short*)(ws + 5767168);   // 512x512 bf16  (0.5 MB)
  unsigned short* Qs    = (unsigned short*)(ws + 6291456);   // [16][2048][64] (4 MB)
  unsigned short* Kp    = (unsigned short*)(ws + 10485760);  // [16][2112][64] (4.125 MB)
  unsigned short* Vp    = (unsigned short*)(ws + 14811136);  // [16][64][2112] (4.125 MB + slack)
  unsigned short* attnb = (unsigned short*)(ws + 19922944);  // 4096x512 bf16 (4 MB)

  hipLaunchKernelGGL(k_prep, dim3(2080), dim3(256), 0, stream,
                     x, xb, Wqkv, wqkvt, Wout, woutt, Kp, Vp);
  hipLaunchKernelGGL((k_gemm<128, 1>), dim3(12, 32), dim3(256), 0, stream,
                     xb, wqkvt, nullptr, (const float*)nullptr, Qs, Kp, Vp, 4096, 1536, 512);
  hipLaunchKernelGGL(k_attn, dim3(512), dim3(256), 0, stream, Qs, Kp, Vp, attnb);
  hipLaunchKernelGGL((k_gemm<64, 0>), dim3(4, 64), dim3(256), 0, stream,
                     attnb, woutt, d_out, bout,
                     (unsigned short*)nullptr, (unsigned short*)nullptr,
                     (unsigned short*)nullptr, 4096, 512, 512);
}

// Round 8
// 41.920 us; speedup vs baseline: 1.2657x; 1.0099x over previous
//
#include <hip/hip_runtime.h>
#include <hip/hip_bf16.h>
#include <stdint.h>

typedef short short8 __attribute__((ext_vector_type(8)));
typedef float f32x4 __attribute__((ext_vector_type(4)));
typedef unsigned short ushort4_t __attribute__((ext_vector_type(4)));
typedef unsigned short ushort8_t __attribute__((ext_vector_type(8)));

#define S_LEN 2048
#define NQKV 1536
#define DMODEL 512

__device__ inline unsigned short f2bf(float f) {
  unsigned int u = __float_as_uint(f);
  unsigned int r = (u + 0x7FFFu + ((u >> 16) & 1u)) >> 16;
  return (unsigned short)r;
}

// async global->LDS, 16B per lane. LDS dest must be linear in lane order.
__device__ __forceinline__ void gll16(const unsigned short* g, unsigned short* l) {
  __builtin_amdgcn_global_load_lds(
      (const __attribute__((address_space(1))) unsigned int*)g,
      (__attribute__((address_space(3))) unsigned int*)l, 16, 0, 0);
}

// ---------------- fused prep: x->bf16, weight transposes, pad zeroing --------
__global__ __launch_bounds__(256) void k_prep(const float* __restrict__ x,
                                              unsigned short* __restrict__ xb,
                                              const float* __restrict__ w1,
                                              unsigned short* __restrict__ o1,
                                              const float* __restrict__ w2,
                                              unsigned short* __restrict__ o2,
                                              unsigned short* __restrict__ Kp,
                                              unsigned short* __restrict__ Vp) {
  __shared__ float T[32][33];
  int bid = blockIdx.x;
  int t = threadIdx.x;
  if (bid < 1024) {
    int i = (bid * 256 + t) * 8;
    float4 a = *(const float4*)(x + i);
    float4 b = *(const float4*)(x + i + 4);
    ushort8_t o;
    o[0] = f2bf(a.x); o[1] = f2bf(a.y); o[2] = f2bf(a.z); o[3] = f2bf(a.w);
    o[4] = f2bf(b.x); o[5] = f2bf(b.y); o[6] = f2bf(b.z); o[7] = f2bf(b.w);
    *(ushort8_t*)(xb + i) = o;
    return;
  }
  if (bid >= 2048) {  // pad zeroing: Kp rows [0,32)+[2080,2112); Vp cols same
    int p = bid - 2048;
    ushort8_t z = {};
    if (p < 16) {
      unsigned short* dst = Kp + (size_t)p * 2112 * 64;
#pragma unroll
      for (int i = 0; i < 2; i++) {
        int s = t + 256 * i;
        int row = s >> 3, c = s & 7;
        int r2 = row < 32 ? row : row - 32 + 2080;
        *(ushort8_t*)&dst[r2 * 64 + c * 8] = z;
      }
    } else {
      unsigned short* dst = Vp + (size_t)(p - 16) * 64 * 2112;
#pragma unroll
      for (int i = 0; i < 2; i++) {
        int s = t + 256 * i;
        int d = s >> 3, side = (s >> 2) & 1, c = s & 3;
        *(ushort8_t*)&dst[(size_t)d * 2112 + side * 2080 + c * 8] = z;
      }
    }
    return;
  }
  bid -= 1024;
  int bx = bid & 63, byy = bid >> 6;
  const float* w; unsigned short* o; int cols;
  if (bx < 48) { w = w1; o = o1; cols = 1536; }
  else         { w = w2; o = o2; cols = 512; bx -= 48; }
  int r0 = byy * 32, c0 = bx * 32;
  int tr = t / 32, tc = t % 32;
#pragma unroll
  for (int i = 0; i < 4; i++) {
    int r = tr + i * 8;
    T[r][tc] = w[(size_t)(r0 + r) * cols + c0 + tc];
  }
  __syncthreads();
#pragma unroll
  for (int i = 0; i < 4; i++) {
    int rr = tr + i * 8;
    o[(size_t)(c0 + rr) * 512 + r0 + tc] = f2bf(T[tc][rr]);
  }
}

// ---------------- GEMM: C[M][N] = A[M][K](bf16) * Bt[N][K](bf16)^T ----------------
// BMxBN tile, BK=32, 4 waves (2x2), global_load_lds staging, 2-phase dbuf.
// MODE 0: f32 out + bias via LDS bounce, coalesced float4 stores.
// MODE 1 (BN=64): block's 64 cols are one pure q/k/v segment; swizzled bounce,
//                 contiguous 16B stores (Qs / Kp shifted / Vp transposed).
template <int BM, int BN, int MODE>
__global__ __launch_bounds__(256) void k_gemm(const unsigned short* __restrict__ A,
                                              const unsigned short* __restrict__ Bt,
                                              void* __restrict__ Cout,
                                              const float* __restrict__ bias,
                                              unsigned short* __restrict__ qs,
                                              unsigned short* __restrict__ kp,
                                              unsigned short* __restrict__ vp,
                                              int M, int N, int K) {
  constexpr int MR = BM / 32, NR = BN / 32;
  constexpr int CA = BM / 64, CB = BN / 64;
  constexpr int STAGE_SH = 2 * (BM + BN) * 32;
  constexpr int BOUNCE_SH = MODE == 0 ? BM * BN * 2 : BM * BN;
  constexpr int SMEM_SH = STAGE_SH > BOUNCE_SH ? STAGE_SH : BOUNCE_SH;
  __shared__ __align__(16) unsigned short smem[SMEM_SH];
  const int ASZ = BM * 32, BOFF = 2 * BM * 32, BSZ = BN * 32;

  const int t = threadIdx.x, lane = t & 63, wid = t >> 6;
  const int m0 = blockIdx.y * BM, n0 = blockIdx.x * BN;
  const int wm = (wid >> 1) * (BM / 2), wn = (wid & 1) * (BN / 2);
  const int lr = lane & 15, kr = (lane >> 4) * 8, lg = lane >> 4;
  const unsigned short* Ab = A + (size_t)m0 * K;
  const unsigned short* Bb = Bt + (size_t)n0 * K;
  f32x4 acc[MR][NR] = {};

  const int NT = K / 32;
  auto stage = [&](int buf, int kt) {
#pragma unroll
    for (int c = 0; c < CA; c++) {
      int f = t + 256 * c;
      gll16(Ab + (size_t)(f >> 2) * K + kt + (f & 3) * 8, &smem[buf * ASZ + f * 8]);
    }
#pragma unroll
    for (int c = 0; c < CB; c++) {
      int f = t + 256 * c;
      gll16(Bb + (size_t)(f >> 2) * K + kt + (f & 3) * 8, &smem[BOFF + buf * BSZ + f * 8]);
    }
  };

  stage(0, 0);
  int buf = 0;
  for (int it = 0; it < NT; ++it) {
    __syncthreads();
    if (it + 1 < NT) stage(buf ^ 1, (it + 1) * 32);
    const unsigned short* Ap = &smem[buf * ASZ];
    const unsigned short* Bp = &smem[BOFF + buf * BSZ];
    short8 af[MR], bfv[NR];
#pragma unroll
    for (int i = 0; i < MR; i++)
      af[i] = *(const short8*)&Ap[(wm + i * 16 + lr) * 32 + kr];
#pragma unroll
    for (int i = 0; i < NR; i++)
      bfv[i] = *(const short8*)&Bp[(wn + i * 16 + lr) * 32 + kr];
#pragma unroll
    for (int mi = 0; mi < MR; mi++)
#pragma unroll
      for (int ni = 0; ni < NR; ni++)
        acc[mi][ni] = __builtin_amdgcn_mfma_f32_16x16x32_bf16(af[mi], bfv[ni], acc[mi][ni], 0, 0, 0);
    buf ^= 1;
  }

  if (MODE == 0) {
    // ---- f32 bounce: [BM][BN] f32, coalesced float4 stores + bias ----
    __syncthreads();
    float* ft = (float*)smem;
#pragma unroll
    for (int mi = 0; mi < MR; mi++)
#pragma unroll
      for (int ni = 0; ni < NR; ni++)
#pragma unroll
        for (int j = 0; j < 4; j++)
          ft[(wm + mi * 16 + lg * 4 + j) * BN + wn + ni * 16 + lr] = acc[mi][ni][j];
    __syncthreads();
#pragma unroll
    for (int i = 0; i < BM * BN / 1024; i++) {
      int s = t + 256 * i;
      int row = s / (BN / 4), ch = s % (BN / 4);
      float4 v = *(const float4*)&ft[row * BN + ch * 4];
      float4 bv = *(const float4*)&bias[n0 + ch * 4];
      v.x += bv.x; v.y += bv.y; v.z += bv.z; v.w += bv.w;
      *(float4*)&((float*)Cout)[(size_t)(m0 + row) * N + n0 + ch * 4] = v;
    }
  } else {
    // ---- swizzled bf16 bounce [BM][64]: u16 idx = row*64 + ((c ^ ((row>>3)&7))*8 + (col&7))
    __syncthreads();
#pragma unroll
    for (int mi = 0; mi < MR; mi++)
#pragma unroll
      for (int ni = 0; ni < NR; ni++)
#pragma unroll
        for (int j = 0; j < 4; j++) {
          int row = wm + mi * 16 + lg * 4 + j;
          int col = wn + ni * 16 + lr;
          smem[row * 64 + (((col >> 3) ^ ((row >> 3) & 7)) << 3) + (col & 7)] =
              f2bf(acc[mi][ni][j]);
        }
    __syncthreads();

    const int b_ = m0 >> 11;
    const int posb = m0 & 2047;
    const int h = n0 / 192, seg = (n0 % 192) >> 6;
    if (seg < 2) {
      unsigned short* dst = (seg == 0)
          ? qs + ((size_t)(b_ * 8 + h) * 2048 + posb) * 64
          : kp + ((size_t)(b_ * 8 + h) * 2112 + 32 + posb) * 64;
#pragma unroll
      for (int i = 0; i < BM / 32; i++) {
        int s = t + 256 * i;              // BM rows x 8 chunks
        int row = s >> 3, ch = s & 7;
        int src = row * 64 + ((ch ^ ((row >> 3) & 7)) << 3);
        *(ushort8_t*)&dst[s * 8] = *(const ushort8_t*)&smem[src];
      }
    } else {
      unsigned short* dst = vp + (size_t)(b_ * 8 + h) * 64 * 2112;
#pragma unroll
      for (int i = 0; i < BM / 32; i++) {
        int s = t + 256 * i;              // dl 0..63, pc 0..BM/8-1
        int dl = s / (BM / 8), pc = s % (BM / 8);
        ushort8_t v;
#pragma unroll
        for (int j = 0; j < 8; j++) {
          int row = pc * 8 + j;
          v[j] = smem[row * 64 + ((((dl >> 3) ^ (pc & 7)) << 3)) + (dl & 7)];
        }
        *(ushort8_t*)&dst[(size_t)dl * 2112 + 32 + posb + pc * 8] = v;
      }
    }
  }
}

// ---------------- windowed attention: LDS-staged, swizzled, branch-free ------
__global__ __launch_bounds__(256) void k_attn(const unsigned short* __restrict__ Qs,
                                              const unsigned short* __restrict__ Kp,
                                              const unsigned short* __restrict__ Vp,
                                              unsigned short* __restrict__ attnb) {
  __shared__ __align__(16) unsigned short Kt[128 * 64];  // pos-local x d, swz
  __shared__ __align__(16) unsigned short Vt[64 * 192];  // d x pos-local, swz
  __shared__ __align__(16) unsigned short Qt[64 * 64];   // q-local x d, swz
  const int t = threadIdx.x, lane = t & 63, w = t >> 6;
  const int blk = blockIdx.x;
  const int sbi = blk & 31, h = (blk >> 5) & 7, b = blk >> 8;
  const int sb = sbi * 64;
  const int bh = b * 8 + h;
  const int lr = lane & 15, lg = lane >> 4;

  {  // stage K: Kp idx sb..sb+127 (= global pos sb-32..sb+95)
    const unsigned short* src = Kp + ((size_t)bh * 2112 + sb) * 64;
#pragma unroll
    for (int i = 0; i < 4; i++) {
      int s = t + 256 * i, row = s >> 3, c = s & 7;
      gll16(src + row * 64 + (c ^ (row & 7)) * 8, &Kt[s * 8]);
    }
  }
  {  // stage V: Vp cols sb..sb+191 (= global pos sb-32..sb+159)
    const unsigned short* src = Vp + (size_t)bh * 64 * 2112 + sb;
#pragma unroll
    for (int i = 0; i < 6; i++) {
      int s = t + 256 * i, d = s / 24, c = s - d * 24;
      gll16(src + (size_t)d * 2112 + (c ^ (d & 7)) * 8, &Vt[s * 8]);
    }
  }
  {  // stage Q: rows sb..sb+63
    const unsigned short* src = Qs + ((size_t)bh * 2048 + sb) * 64;
#pragma unroll
    for (int i = 0; i < 2; i++) {
      int s = t + 256 * i, row = s >> 3, c = s & 7;
      gll16(src + row * 64 + (c ^ (row & 7)) * 8, &Qt[s * 8]);
    }
  }
  __syncthreads();

  const int sw = (lr & 7) << 3;  // u16 read-XOR (16B chunks)

  short8 qb[2];
#pragma unroll
  for (int ks = 0; ks < 2; ks++)
    qb[ks] = *(const short8*)&Qt[(w * 16 + lr) * 64 + ((ks * 32 + lg * 8) ^ sw)];

  // S^T: col = q = lr, row = pos_local(rel s0-32) = ct*16 + lg*4 + j
  f32x4 sc[5] = {};
#pragma unroll
  for (int ct = 0; ct < 5; ct++) {
#pragma unroll
    for (int ks = 0; ks < 2; ks++) {
      short8 ka = *(const short8*)&Kt[(w * 16 + ct * 16 + lr) * 64 + ((ks * 32 + lg * 8) ^ sw)];
      sc[ct] = __builtin_amdgcn_mfma_f32_16x16x32_bf16(ka, qb[ks], sc[ct], 0, 0, 0);
    }
  }

  float mx = -1e30f;
#pragma unroll
  for (int ct = 0; ct < 5; ct++)
#pragma unroll
    for (int j = 0; j < 4; j++) {
      int c2 = ct * 16 + lg * 4 + j;
      sc[ct][j] = (c2 >= lr && c2 <= lr + 64) ? sc[ct][j] * 0.125f : -1e30f;
      mx = fmaxf(mx, sc[ct][j]);
    }
  mx = fmaxf(mx, __shfl_xor(mx, 16, 64));
  mx = fmaxf(mx, __shfl_xor(mx, 32, 64));

  float pn[5][4];
  float sum = 0.0f;
#pragma unroll
  for (int ct = 0; ct < 5; ct++)
#pragma unroll
    for (int j = 0; j < 4; j++) {
      pn[ct][j] = __expf(sc[ct][j] - mx);
      sum += pn[ct][j];
    }
  sum += __shfl_xor(sum, 16, 64);
  sum += __shfl_xor(sum, 32, 64);
  float inv = 1.0f / sum;

  unsigned int w01[5], w23[5];
#pragma unroll
  for (int ct = 0; ct < 5; ct++) {
    w01[ct] = (unsigned int)f2bf(pn[ct][0] * inv) | ((unsigned int)f2bf(pn[ct][1] * inv) << 16);
    w23[ct] = (unsigned int)f2bf(pn[ct][2] * inv) | ((unsigned int)f2bf(pn[ct][3] * inv) << 16);
  }

  f32x4 oa[4] = {};
  const int h2 = lg & 1, tl = lg >> 1;
  const int sA = 32 * h2 + lr, sB = sA + 16;
#pragma unroll
  for (int ks = 0; ks < 3; ks++) {
    const int T0 = 2 * ks;
    const int T1 = (2 * ks + 1 < 5) ? (2 * ks + 1) : 4;
    unsigned int a0 = __shfl((int)w01[T0], sA, 64), a1 = __shfl((int)w23[T0], sA, 64);
    unsigned int a2 = __shfl((int)w01[T0], sB, 64), a3 = __shfl((int)w23[T0], sB, 64);
    unsigned int b0 = __shfl((int)w01[T1], sA, 64), b1 = __shfl((int)w23[T1], sA, 64);
    unsigned int b2 = __shfl((int)w01[T1], sB, 64), b3 = __shfl((int)w23[T1], sB, 64);
    union { unsigned int u[4]; short8 v; } pb;
    pb.u[0] = tl ? b0 : a0;
    pb.u[1] = tl ? b1 : a1;
    pb.u[2] = tl ? b2 : a2;
    pb.u[3] = tl ? b3 : a3;
    if (ks == 2 && tl) { pb.u[0] = 0; pb.u[1] = 0; pb.u[2] = 0; pb.u[3] = 0; }
    int pofl = w * 16 + ks * 32 + lg * 8;
#pragma unroll
    for (int nt = 0; nt < 4; nt++) {
      short8 va = *(const short8*)&Vt[(nt * 16 + lr) * 192 + (pofl ^ sw)];
      oa[nt] = __builtin_amdgcn_mfma_f32_16x16x32_bf16(va, pb.v, oa[nt], 0, 0, 0);
    }
  }

  const int s0 = sb + w * 16;
#pragma unroll
  for (int nt = 0; nt < 4; nt++) {
    ushort4_t o;
#pragma unroll
    for (int j = 0; j < 4; j++) o[j] = f2bf(oa[nt][j]);
    *(ushort4_t*)&attnb[((size_t)b * S_LEN + s0 + lr) * DMODEL + h * 64 + nt * 16 + lg * 4] = o;
  }
}

// ---------------- launch ----------------
extern "C" void kernel_launch(void* const* d_in, const int* in_sizes, int n_in,
                              void* d_out, int out_size, void* d_ws, size_t ws_size,
                              hipStream_t stream) {
  const float* x    = (const float*)d_in[0];
  const float* Wqkv = (const float*)d_in[1];
  const float* Wout = (const float*)d_in[2];
  const float* bout = (const float*)d_in[3];
  char* ws = (char*)d_ws;
  unsigned short* xb    = (unsigned short*)(ws + 0);         // 4096x512 bf16 (4 MB)
  unsigned short* wqkvt = (unsigned short*)(ws + 4194304);   // 1536x512 bf16 (1.5 MB)
  unsigned short* woutt = (unsigned short*)(ws + 5767168);   // 512x512 bf16  (0.5 MB)
  unsigned short* Qs    = (unsigned short*)(ws + 6291456);   // [16][2048][64] (4 MB)
  unsigned short* Kp    = (unsigned short*)(ws + 10485760);  // [16][2112][64] (4.125 MB)
  unsigned short* Vp    = (unsigned short*)(ws + 14811136);  // [16][64][2112] (4.125 MB + slack)
  unsigned short* attnb = (unsigned short*)(ws + 19922944);  // 4096x512 bf16 (4 MB)

  hipLaunchKernelGGL(k_prep, dim3(2080), dim3(256), 0, stream,
                     x, xb, Wqkv, wqkvt, Wout, woutt, Kp, Vp);
  hipLaunchKernelGGL((k_gemm<128, 64, 1>), dim3(24, 32), dim3(256), 0, stream,
                     xb, wqkvt, nullptr, (const float*)nullptr, Qs, Kp, Vp, 4096, 1536, 512);
  hipLaunchKernelGGL(k_attn, dim3(512), dim3(256), 0, stream, Qs, Kp, Vp, attnb);
  hipLaunchKernelGGL((k_gemm<64, 64, 0>), dim3(8, 64), dim3(256), 0, stream,
                     attnb, woutt, d_out, bout,
                     (unsigned short*)nullptr, (unsigned short*)nullptr,
                     (unsigned short*)nullptr, 4096, 512, 512);
}

// Round 9
// 37.115 us; speedup vs baseline: 1.4296x; 1.1295x over previous
//
#include <hip/hip_runtime.h>
#include <hip/hip_bf16.h>
#include <stdint.h>

typedef short short8 __attribute__((ext_vector_type(8)));
typedef float f32x4 __attribute__((ext_vector_type(4)));
typedef unsigned short ushort4_t __attribute__((ext_vector_type(4)));
typedef unsigned short ushort8_t __attribute__((ext_vector_type(8)));

#define S_LEN 2048
#define NQKV 1536
#define DMODEL 512

__device__ inline unsigned short f2bf(float f) {
  unsigned int u = __float_as_uint(f);
  unsigned int r = (u + 0x7FFFu + ((u >> 16) & 1u)) >> 16;
  return (unsigned short)r;
}

// async global->LDS, 16B per lane. LDS dest must be linear in lane order.
__device__ __forceinline__ void gll16(const unsigned short* g, unsigned short* l) {
  __builtin_amdgcn_global_load_lds(
      (const __attribute__((address_space(1))) unsigned int*)g,
      (__attribute__((address_space(3))) unsigned int*)l, 16, 0, 0);
}

// ---------------- fused prep: x->bf16, weight transposes, pad zeroing --------
__global__ __launch_bounds__(256) void k_prep(const float* __restrict__ x,
                                              unsigned short* __restrict__ xb,
                                              const float* __restrict__ w1,
                                              unsigned short* __restrict__ o1,
                                              const float* __restrict__ w2,
                                              unsigned short* __restrict__ o2,
                                              unsigned short* __restrict__ Kp,
                                              unsigned short* __restrict__ Vp) {
  __shared__ float T[32][33];
  int bid = blockIdx.x;
  int t = threadIdx.x;
  if (bid < 1024) {
    int i = (bid * 256 + t) * 8;
    float4 a = *(const float4*)(x + i);
    float4 b = *(const float4*)(x + i + 4);
    ushort8_t o;
    o[0] = f2bf(a.x); o[1] = f2bf(a.y); o[2] = f2bf(a.z); o[3] = f2bf(a.w);
    o[4] = f2bf(b.x); o[5] = f2bf(b.y); o[6] = f2bf(b.z); o[7] = f2bf(b.w);
    *(ushort8_t*)(xb + i) = o;
    return;
  }
  if (bid >= 2048) {  // pad zeroing: Kp rows [0,32)+[2080,2112); Vp cols same
    int p = bid - 2048;
    ushort8_t z = {};
    if (p < 16) {
      unsigned short* dst = Kp + (size_t)p * 2112 * 64;
#pragma unroll
      for (int i = 0; i < 2; i++) {
        int s = t + 256 * i;
        int row = s >> 3, c = s & 7;
        int r2 = row < 32 ? row : row - 32 + 2080;
        *(ushort8_t*)&dst[r2 * 64 + c * 8] = z;
      }
    } else {
      unsigned short* dst = Vp + (size_t)(p - 16) * 64 * 2112;
#pragma unroll
      for (int i = 0; i < 2; i++) {
        int s = t + 256 * i;
        int d = s >> 3, side = (s >> 2) & 1, c = s & 3;
        *(ushort8_t*)&dst[(size_t)d * 2112 + side * 2080 + c * 8] = z;
      }
    }
    return;
  }
  bid -= 1024;
  int bx = bid & 63, byy = bid >> 6;
  const float* w; unsigned short* o; int cols;
  if (bx < 48) { w = w1; o = o1; cols = 1536; }
  else         { w = w2; o = o2; cols = 512; bx -= 48; }
  int r0 = byy * 32, c0 = bx * 32;
  int tr = t / 32, tc = t % 32;
#pragma unroll
  for (int i = 0; i < 4; i++) {
    int r = tr + i * 8;
    T[r][tc] = w[(size_t)(r0 + r) * cols + c0 + tc];
  }
  __syncthreads();
#pragma unroll
  for (int i = 0; i < 4; i++) {
    int rr = tr + i * 8;
    o[(size_t)(c0 + rr) * 512 + r0 + tc] = f2bf(T[tc][rr]);
  }
}

// ---------------- GEMM: C[M][N] = A[M][K](bf16) * Bt[N][K](bf16)^T ----------------
// BMxBN tile, BK=64, 4 waves (2x2), global_load_lds staging (both-sides XOR
// swizzle: pre-swizzled global source chunk + same XOR on ds_read -> 2-way),
// 2-phase double buffer (8 barriers for K=512, was 16 at BK=32).
// MODE 0: f32 out + bias via LDS bounce, coalesced float4 stores.
// MODE 1 (BN=64): block's 64 cols are one pure q/k/v segment; swizzled bounce,
//                 contiguous 16B stores (Qs / Kp shifted / Vp transposed).
template <int BM, int BN, int MODE>
__global__ __launch_bounds__(256) void k_gemm(const unsigned short* __restrict__ A,
                                              const unsigned short* __restrict__ Bt,
                                              void* __restrict__ Cout,
                                              const float* __restrict__ bias,
                                              unsigned short* __restrict__ qs,
                                              unsigned short* __restrict__ kp,
                                              unsigned short* __restrict__ vp,
                                              int M, int N, int K) {
  constexpr int MR = BM / 32, NR = BN / 32;
  constexpr int CA = BM / 32, CB = BN / 32;        // 16B chunks/thread at BK=64
  constexpr int STAGE_SH = 2 * (BM + BN) * 64;
  constexpr int BOUNCE_SH = MODE == 0 ? BM * BN * 2 : BM * BN;
  constexpr int SMEM_SH = STAGE_SH > BOUNCE_SH ? STAGE_SH : BOUNCE_SH;
  __shared__ __align__(16) unsigned short smem[SMEM_SH];
  const int ASZ = BM * 64, BOFF = 2 * BM * 64, BSZ = BN * 64;

  const int t = threadIdx.x, lane = t & 63, wid = t >> 6;
  const int m0 = blockIdx.y * BM, n0 = blockIdx.x * BN;
  const int wm = (wid >> 1) * (BM / 2), wn = (wid & 1) * (BN / 2);
  const int lr = lane & 15, lg = lane >> 4;
  const unsigned short* Ab = A + (size_t)m0 * K;
  const unsigned short* Bb = Bt + (size_t)n0 * K;
  f32x4 acc[MR][NR] = {};

  const int NT = K / 64;
  auto stage = [&](int buf, int kt) {
#pragma unroll
    for (int c = 0; c < CA; c++) {
      int f = t + 256 * c;
      int row = f >> 3, ch = f & 7;
      gll16(Ab + (size_t)row * K + kt + ((ch ^ (row & 7)) << 3),
            &smem[buf * ASZ + f * 8]);
    }
#pragma unroll
    for (int c = 0; c < CB; c++) {
      int f = t + 256 * c;
      int row = f >> 3, ch = f & 7;
      gll16(Bb + (size_t)row * K + kt + ((ch ^ (row & 7)) << 3),
            &smem[BOFF + buf * BSZ + f * 8]);
    }
  };

  stage(0, 0);
  int buf = 0;
  for (int it = 0; it < NT; ++it) {
    __syncthreads();
    if (it + 1 < NT) stage(buf ^ 1, (it + 1) * 64);
    const unsigned short* Ap = &smem[buf * ASZ];
    const unsigned short* Bp = &smem[BOFF + buf * BSZ];
#pragma unroll
    for (int sl = 0; sl < 2; sl++) {
      const int cs = sl * 4 + lg;                  // 16B chunk within the row
      short8 af[MR], bfv[NR];
#pragma unroll
      for (int i = 0; i < MR; i++) {
        int row = wm + i * 16 + lr;
        af[i] = *(const short8*)&Ap[row * 64 + ((cs ^ (row & 7)) << 3)];
      }
#pragma unroll
      for (int i = 0; i < NR; i++) {
        int row = wn + i * 16 + lr;
        bfv[i] = *(const short8*)&Bp[row * 64 + ((cs ^ (row & 7)) << 3)];
      }
#pragma unroll
      for (int mi = 0; mi < MR; mi++)
#pragma unroll
        for (int ni = 0; ni < NR; ni++)
          acc[mi][ni] = __builtin_amdgcn_mfma_f32_16x16x32_bf16(af[mi], bfv[ni], acc[mi][ni], 0, 0, 0);
    }
    buf ^= 1;
  }

  if (MODE == 0) {
    // ---- f32 bounce: [BM][BN] f32, coalesced float4 stores + bias ----
    __syncthreads();
    float* ft = (float*)smem;
#pragma unroll
    for (int mi = 0; mi < MR; mi++)
#pragma unroll
      for (int ni = 0; ni < NR; ni++)
#pragma unroll
        for (int j = 0; j < 4; j++)
          ft[(wm + mi * 16 + lg * 4 + j) * BN + wn + ni * 16 + lr] = acc[mi][ni][j];
    __syncthreads();
#pragma unroll
    for (int i = 0; i < BM * BN / 1024; i++) {
      int s = t + 256 * i;
      int row = s / (BN / 4), ch = s % (BN / 4);
      float4 v = *(const float4*)&ft[row * BN + ch * 4];
      float4 bv = *(const float4*)&bias[n0 + ch * 4];
      v.x += bv.x; v.y += bv.y; v.z += bv.z; v.w += bv.w;
      *(float4*)&((float*)Cout)[(size_t)(m0 + row) * N + n0 + ch * 4] = v;
    }
  } else {
    // ---- swizzled bf16 bounce [BM][64]: u16 idx = row*64 + ((c ^ ((row>>3)&7))*8 + (col&7))
    __syncthreads();
#pragma unroll
    for (int mi = 0; mi < MR; mi++)
#pragma unroll
      for (int ni = 0; ni < NR; ni++)
#pragma unroll
        for (int j = 0; j < 4; j++) {
          int row = wm + mi * 16 + lg * 4 + j;
          int col = wn + ni * 16 + lr;
          smem[row * 64 + (((col >> 3) ^ ((row >> 3) & 7)) << 3) + (col & 7)] =
              f2bf(acc[mi][ni][j]);
        }
    __syncthreads();

    const int b_ = m0 >> 11;
    const int posb = m0 & 2047;
    const int h = n0 / 192, seg = (n0 % 192) >> 6;
    if (seg < 2) {
      unsigned short* dst = (seg == 0)
          ? qs + ((size_t)(b_ * 8 + h) * 2048 + posb) * 64
          : kp + ((size_t)(b_ * 8 + h) * 2112 + 32 + posb) * 64;
#pragma unroll
      for (int i = 0; i < BM / 32; i++) {
        int s = t + 256 * i;              // BM rows x 8 chunks
        int row = s >> 3, ch = s & 7;
        int src = row * 64 + ((ch ^ ((row >> 3) & 7)) << 3);
        *(ushort8_t*)&dst[s * 8] = *(const ushort8_t*)&smem[src];
      }
    } else {
      unsigned short* dst = vp + (size_t)(b_ * 8 + h) * 64 * 2112;
#pragma unroll
      for (int i = 0; i < BM / 32; i++) {
        int s = t + 256 * i;              // dl 0..63, pc 0..BM/8-1
        int dl = s / (BM / 8), pc = s % (BM / 8);
        ushort8_t v;
#pragma unroll
        for (int j = 0; j < 8; j++) {
          int row = pc * 8 + j;
          v[j] = smem[row * 64 + ((((dl >> 3) ^ (pc & 7)) << 3)) + (dl & 7)];
        }
        *(ushort8_t*)&dst[(size_t)dl * 2112 + 32 + posb + pc * 8] = v;
      }
    }
  }
}

// ---------------- windowed attention: LDS-staged, swizzled, branch-free ------
__global__ __launch_bounds__(256) void k_attn(const unsigned short* __restrict__ Qs,
                                              const unsigned short* __restrict__ Kp,
                                              const unsigned short* __restrict__ Vp,
                                              unsigned short* __restrict__ attnb) {
  __shared__ __align__(16) unsigned short Kt[128 * 64];  // pos-local x d, swz
  __shared__ __align__(16) unsigned short Vt[64 * 192];  // d x pos-local, swz
  __shared__ __align__(16) unsigned short Qt[64 * 64];   // q-local x d, swz
  const int t = threadIdx.x, lane = t & 63, w = t >> 6;
  const int blk = blockIdx.x;
  const int sbi = blk & 31, h = (blk >> 5) & 7, b = blk >> 8;
  const int sb = sbi * 64;
  const int bh = b * 8 + h;
  const int lr = lane & 15, lg = lane >> 4;

  {  // stage K: Kp idx sb..sb+127 (= global pos sb-32..sb+95)
    const unsigned short* src = Kp + ((size_t)bh * 2112 + sb) * 64;
#pragma unroll
    for (int i = 0; i < 4; i++) {
      int s = t + 256 * i, row = s >> 3, c = s & 7;
      gll16(src + row * 64 + (c ^ (row & 7)) * 8, &Kt[s * 8]);
    }
  }
  {  // stage V: Vp cols sb..sb+191 (= global pos sb-32..sb+159)
    const unsigned short* src = Vp + (size_t)bh * 64 * 2112 + sb;
#pragma unroll
    for (int i = 0; i < 6; i++) {
      int s = t + 256 * i, d = s / 24, c = s - d * 24;
      gll16(src + (size_t)d * 2112 + (c ^ (d & 7)) * 8, &Vt[s * 8]);
    }
  }
  {  // stage Q: rows sb..sb+63
    const unsigned short* src = Qs + ((size_t)bh * 2048 + sb) * 64;
#pragma unroll
    for (int i = 0; i < 2; i++) {
      int s = t + 256 * i, row = s >> 3, c = s & 7;
      gll16(src + row * 64 + (c ^ (row & 7)) * 8, &Qt[s * 8]);
    }
  }
  __syncthreads();

  const int sw = (lr & 7) << 3;  // u16 read-XOR (16B chunks)

  short8 qb[2];
#pragma unroll
  for (int ks = 0; ks < 2; ks++)
    qb[ks] = *(const short8*)&Qt[(w * 16 + lr) * 64 + ((ks * 32 + lg * 8) ^ sw)];

  // S^T: col = q = lr, row = pos_local(rel s0-32) = ct*16 + lg*4 + j
  f32x4 sc[5] = {};
#pragma unroll
  for (int ct = 0; ct < 5; ct++) {
#pragma unroll
    for (int ks = 0; ks < 2; ks++) {
      short8 ka = *(const short8*)&Kt[(w * 16 + ct * 16 + lr) * 64 + ((ks * 32 + lg * 8) ^ sw)];
      sc[ct] = __builtin_amdgcn_mfma_f32_16x16x32_bf16(ka, qb[ks], sc[ct], 0, 0, 0);
    }
  }

  float mx = -1e30f;
#pragma unroll
  for (int ct = 0; ct < 5; ct++)
#pragma unroll
    for (int j = 0; j < 4; j++) {
      int c2 = ct * 16 + lg * 4 + j;
      sc[ct][j] = (c2 >= lr && c2 <= lr + 64) ? sc[ct][j] * 0.125f : -1e30f;
      mx = fmaxf(mx, sc[ct][j]);
    }
  mx = fmaxf(mx, __shfl_xor(mx, 16, 64));
  mx = fmaxf(mx, __shfl_xor(mx, 32, 64));

  float pn[5][4];
  float sum = 0.0f;
#pragma unroll
  for (int ct = 0; ct < 5; ct++)
#pragma unroll
    for (int j = 0; j < 4; j++) {
      pn[ct][j] = __expf(sc[ct][j] - mx);
      sum += pn[ct][j];
    }
  sum += __shfl_xor(sum, 16, 64);
  sum += __shfl_xor(sum, 32, 64);
  float inv = 1.0f / sum;

  unsigned int w01[5], w23[5];
#pragma unroll
  for (int ct = 0; ct < 5; ct++) {
    w01[ct] = (unsigned int)f2bf(pn[ct][0] * inv) | ((unsigned int)f2bf(pn[ct][1] * inv) << 16);
    w23[ct] = (unsigned int)f2bf(pn[ct][2] * inv) | ((unsigned int)f2bf(pn[ct][3] * inv) << 16);
  }

  f32x4 oa[4] = {};
  const int h2 = lg & 1, tl = lg >> 1;
  const int sA = 32 * h2 + lr, sB = sA + 16;
#pragma unroll
  for (int ks = 0; ks < 3; ks++) {
    const int T0 = 2 * ks;
    const int T1 = (2 * ks + 1 < 5) ? (2 * ks + 1) : 4;
    unsigned int a0 = __shfl((int)w01[T0], sA, 64), a1 = __shfl((int)w23[T0], sA, 64);
    unsigned int a2 = __shfl((int)w01[T0], sB, 64), a3 = __shfl((int)w23[T0], sB, 64);
    unsigned int b0 = __shfl((int)w01[T1], sA, 64), b1 = __shfl((int)w23[T1], sA, 64);
    unsigned int b2 = __shfl((int)w01[T1], sB, 64), b3 = __shfl((int)w23[T1], sB, 64);
    union { unsigned int u[4]; short8 v; } pb;
    pb.u[0] = tl ? b0 : a0;
    pb.u[1] = tl ? b1 : a1;
    pb.u[2] = tl ? b2 : a2;
    pb.u[3] = tl ? b3 : a3;
    if (ks == 2 && tl) { pb.u[0] = 0; pb.u[1] = 0; pb.u[2] = 0; pb.u[3] = 0; }
    int pofl = w * 16 + ks * 32 + lg * 8;
#pragma unroll
    for (int nt = 0; nt < 4; nt++) {
      short8 va = *(const short8*)&Vt[(nt * 16 + lr) * 192 + (pofl ^ sw)];
      oa[nt] = __builtin_amdgcn_mfma_f32_16x16x32_bf16(va, pb.v, oa[nt], 0, 0, 0);
    }
  }

  const int s0 = sb + w * 16;
#pragma unroll
  for (int nt = 0; nt < 4; nt++) {
    ushort4_t o;
#pragma unroll
    for (int j = 0; j < 4; j++) o[j] = f2bf(oa[nt][j]);
    *(ushort4_t*)&attnb[((size_t)b * S_LEN + s0 + lr) * DMODEL + h * 64 + nt * 16 + lg * 4] = o;
  }
}

// ---------------- launch ----------------
extern "C" void kernel_launch(void* const* d_in, const int* in_sizes, int n_in,
                              void* d_out, int out_size, void* d_ws, size_t ws_size,
                              hipStream_t stream) {
  const float* x    = (const float*)d_in[0];
  const float* Wqkv = (const float*)d_in[1];
  const float* Wout = (const float*)d_in[2];
  const float* bout = (const float*)d_in[3];
  char* ws = (char*)d_ws;
  unsigned short* xb    = (unsigned short*)(ws + 0);         // 4096x512 bf16 (4 MB)
  unsigned short* wqkvt = (unsigned short*)(ws + 4194304);   // 1536x512 bf16 (1.5 MB)
  unsigned short* woutt = (unsigned short*)(ws + 5767168);   // 512x512 bf16  (0.5 MB)
  unsigned short* Qs    = (unsigned short*)(ws + 6291456);   // [16][2048][64] (4 MB)
  unsigned short* Kp    = (unsigned short*)(ws + 10485760);  // [16][2112][64] (4.125 MB)
  unsigned short* Vp    = (unsigned short*)(ws + 14811136);  // [16][64][2112] (4.125 MB + slack)
  unsigned short* attnb = (unsigned short*)(ws + 19922944);  // 4096x512 bf16 (4 MB)

  hipLaunchKernelGGL(k_prep, dim3(2080), dim3(256), 0, stream,
                     x, xb, Wqkv, wqkvt, Wout, woutt, Kp, Vp);
  hipLaunchKernelGGL((k_gemm<128, 64, 1>), dim3(24, 32), dim3(256), 0, stream,
                     xb, wqkvt, nullptr, (const float*)nullptr, Qs, Kp, Vp, 4096, 1536, 512);
  hipLaunchKernelGGL(k_attn, dim3(512), dim3(256), 0, stream, Qs, Kp, Vp, attnb);
  hipLaunchKernelGGL((k_gemm<64, 64, 0>), dim3(8, 64), dim3(256), 0, stream,
                     attnb, woutt, d_out, bout,
                     (unsigned short*)nullptr, (unsigned short*)nullptr,
                     (unsigned short*)nullptr, 4096, 512, 512);
}